// Round 4
// baseline (1205.170 us; speedup 1.0000x reference)
//
#include <hip/hip_runtime.h>
#include <math.h>

// BATCH=128, IN_CH=OUT_CH=64, DIM=4096, HALF=2049 (=MODES)
#define NFFT 4096
#define MH   2048          // NFFT/2, complex FFT size for the real-FFT trick
#define HALF 2049
#define NSIG 8192          // 128*64
#define KT   32            // modes per k-tile
#define NKT  65            // ceil(2049/32)

__device__ __forceinline__ float2 cmulf(float2 a, float2 b) {
  return make_float2(a.x*b.x - a.y*b.y, a.x*b.y + a.y*b.x);
}

// ---------------- K1: rfft(4096) via 2048-pt complex Stockham + unpack + phase align ----
// writes z in tiled layout z[kt][bi][kk], kt=k>>5, kk=k&31
__global__ __launch_bounds__(256) void k_rfft_phase(
    const float* __restrict__ x, float2* __restrict__ z, float* __restrict__ phi0) {
  __shared__ float2 bufA[MH];
  __shared__ float2 bufB[MH];
  const int bi  = blockIdx.x;        // b*64 + i
  const int tid = threadIdx.x;
  // pack: y[n] = x[2n] + i x[2n+1]  == reinterpret row as float2
  const float2* xp = (const float2*)(x + (size_t)bi * NFFT);
  for (int j = tid; j < MH; j += 256) bufA[j] = xp[j];
  __syncthreads();

  float2* src = bufA; float2* dst = bufB;
  #pragma unroll 1
  for (int st = 0; st < 11; ++st) {
    const int n  = MH >> st;
    const float tw = -6.283185307179586f / (float)n;   // forward twiddles
    #pragma unroll
    for (int jj = 0; jj < 4; ++jj) {
      const int j = tid + jj * 256;       // 0..1023
      const int p = j >> st;
      const int q = j & ((1 << st) - 1);
      float2 a = src[q + (p << st)];
      float2 b = src[q + (p << st) + 1024];
      float sn, cs; __sincosf(tw * (float)p, &sn, &cs);
      float2 d = make_float2(a.x - b.x, a.y - b.y);
      dst[q + (p << (st + 1))]             = make_float2(a.x + b.x, a.y + b.y);
      dst[q + (p << (st + 1)) + (1 << st)] = make_float2(d.x*cs - d.y*sn, d.x*sn + d.y*cs);
    }
    __syncthreads();
    float2* t = src; src = dst; dst = t;
  }
  // 11 stages (odd): Y lives in bufB (== src). Unpack Z[k], k=0..2047 into bufA (== dst).
  float2* Y = src; float2* Z = dst;
  for (int k = tid; k < MH; k += 256) {
    const float2 Yk = Y[k];
    const float2 Ym = Y[(MH - k) & (MH - 1)];
    const float2 E = make_float2(0.5f*(Yk.x + Ym.x), 0.5f*(Yk.y - Ym.y)); // 0.5(Yk+conj(Ym))
    const float2 D = make_float2(0.5f*(Yk.x - Ym.x), 0.5f*(Yk.y + Ym.y)); // 0.5(Yk-conj(Ym))
    const float th = 6.283185307179586f * (float)k / (float)NFFT;
    float sn, cs; __sincosf(th, &sn, &cs);
    // Z = E + cmul((-sn,-cs), D)
    Z[k] = make_float2(E.x + (-sn*D.x + cs*D.y), E.y + (-sn*D.y - cs*D.x));
  }
  __syncthreads();

  const float phi = atan2f(Z[1].y, Z[1].x);            // angle of UNROTATED Z[1]
  if (tid == 0 && (bi & 63) == 0) phi0[bi >> 6] = phi;

  for (int k = tid; k < HALF; k += 256) {
    float2 Zk;
    if (k < MH) Zk = Z[k];
    else        Zk = make_float2(Y[0].x - Y[0].y, 0.0f);   // Z[2048] = ReY0 - ImY0
    const int kin = (k <= 1024) ? k : k - HALF;
    double rev = (double)phi * (double)kin * 0.15915494309189535;
    rev -= rint(rev);
    const float thr = (float)(rev * 6.283185307179586);
    float sn, cs; __sincosf(thr, &sn, &cs);
    // multiply by e^{-i thr}
    const float2 r = make_float2(Zk.x*cs + Zk.y*sn, Zk.y*cs - Zk.x*sn);
    const int kt = k >> 5, kk = k & 31;
    z[((size_t)kt * NSIG + bi) * KT + kk] = r;
  }
}

// ---------------- K2: per-mode complex GEMM + bias + e^{+i phi0 k_out}, IN-PLACE ----------
// zio[kt][bi][kk] -> (same storage) zio[kt][bo][kk].  Block = (4 b) x (64 o) x (32 kk).
__global__ __launch_bounds__(256) void k_gemm_mode(
    float2* __restrict__ zio,
    const float* __restrict__ wr, const float* __restrict__ wi,
    const float* __restrict__ br, const float* __restrict__ bim,
    const float* __restrict__ phi0) {
  const int t  = threadIdx.x;
  const int kk = t & 31;
  const int g  = t >> 5;              // 0..7 -> o0 = g*8
  const int kt = blockIdx.y;
  const int b0 = blockIdx.x * 4;
  const int k  = kt * KT + kk;
  const bool kvalid = (k < HALF);
  const int kc = kvalid ? k : (HALF - 1);   // clamp for global reads
  const int o0 = g * 8;

  float2 acc[4][8];
  #pragma unroll
  for (int bb = 0; bb < 4; ++bb)
    #pragma unroll
    for (int oo = 0; oo < 8; ++oo) acc[bb][oo] = make_float2(0.f, 0.f);

  const float2* zbase = zio + (size_t)kt * NSIG * KT + kk;
  const float*  wrp = wr + (size_t)o0 * HALF + kc;
  const float*  wip = wi + (size_t)o0 * HALF + kc;

  #pragma unroll 1
  for (int i = 0; i < 64; ++i) {
    float2 zv[4];
    #pragma unroll
    for (int bb = 0; bb < 4; ++bb)
      zv[bb] = zbase[(size_t)((b0 + bb) * 64 + i) * KT];
    const size_t wi_off = (size_t)i * 64 * HALF;
    #pragma unroll
    for (int oo = 0; oo < 8; ++oo) {
      const float wrv = wrp[wi_off + (size_t)oo * HALF];
      const float wiv = wip[wi_off + (size_t)oo * HALF];
      #pragma unroll
      for (int bb = 0; bb < 4; ++bb) {
        acc[bb][oo].x += zv[bb].x * wrv - zv[bb].y * wiv;
        acc[bb][oo].y += zv[bb].x * wiv + zv[bb].y * wrv;
      }
    }
  }
  __syncthreads();   // all z reads of this block's region complete before overwrite

  const int kout = (k <= 1024) ? k : k - HALF;
  #pragma unroll
  for (int bb = 0; bb < 4; ++bb) {
    double rev = (double)phi0[b0 + bb] * (double)kout * 0.15915494309189535;
    rev -= rint(rev);
    const float th = (float)(rev * 6.283185307179586);
    float sn, cs; __sincosf(th, &sn, &cs);
    const float2 rot = make_float2(cs, sn);
    #pragma unroll
    for (int oo = 0; oo < 8; ++oo) {
      const int o = o0 + oo;
      const float2 v = make_float2(acc[bb][oo].x + br[(size_t)o * HALF + kc],
                                   acc[bb][oo].y + bim[(size_t)o * HALF + kc]);
      if (kvalid)
        zio[((size_t)kt * NSIG + (size_t)(b0 + bb) * 64 + o) * KT + kk] = cmulf(v, rot);
    }
  }
}

// ---------------- K3: irfft(4096) via pack + 2048-pt inverse Stockham ----------------
__global__ __launch_bounds__(256) void k_irfft(
    const float2* __restrict__ oft, float* __restrict__ out) {
  __shared__ float2 bufA[MH];
  __shared__ float2 bufB[MH];
  __shared__ float2 zNyq;
  const int bo  = blockIdx.x;     // b*64 + o
  const int tid = threadIdx.x;
  for (int k = tid; k < HALF; k += 256) {
    const int kt = k >> 5, kk = k & 31;
    float2 v = oft[((size_t)kt * NSIG + bo) * KT + kk];
    if (k == 0) v.y = 0.f;                    // c2r drops imag of DC/Nyquist
    if (k == MH) zNyq = make_float2(v.x, 0.f);
    else         bufB[k] = v;
  }
  __syncthreads();
  // Y[k] = 0.5*(A + i e^{+2pi i k/N} D),  A=Zk+conj(Zm), D=Zk-conj(Zm), m=2048-k
  for (int k = tid; k < MH; k += 256) {
    const float2 Zk = bufB[k];
    const float2 Zm = (k == 0) ? zNyq : bufB[MH - k];
    const float2 A = make_float2(Zk.x + Zm.x, Zk.y - Zm.y);
    const float2 D = make_float2(Zk.x - Zm.x, Zk.y + Zm.y);
    const float th = 6.283185307179586f * (float)k / (float)NFFT;
    float sn, cs; __sincosf(th, &sn, &cs);
    // B = cmul((-sn, cs), D);  Y = 0.5 (A + B)
    bufA[k] = make_float2(0.5f*(A.x + (-sn*D.x - cs*D.y)),
                          0.5f*(A.y + (-sn*D.y + cs*D.x)));
  }
  __syncthreads();

  float2* src = bufA; float2* dst = bufB;
  #pragma unroll 1
  for (int st = 0; st < 11; ++st) {
    const int n  = MH >> st;
    const float tw = 6.283185307179586f / (float)n;    // inverse twiddles
    #pragma unroll
    for (int jj = 0; jj < 4; ++jj) {
      const int j = tid + jj * 256;
      const int p = j >> st;
      const int q = j & ((1 << st) - 1);
      float2 a = src[q + (p << st)];
      float2 b = src[q + (p << st) + 1024];
      float sn, cs; __sincosf(tw * (float)p, &sn, &cs);
      float2 d = make_float2(a.x - b.x, a.y - b.y);
      dst[q + (p << (st + 1))]             = make_float2(a.x + b.x, a.y + b.y);
      dst[q + (p << (st + 1)) + (1 << st)] = make_float2(d.x*cs - d.y*sn, d.x*sn + d.y*cs);
    }
    __syncthreads();
    float2* t = src; src = dst; dst = t;
  }
  // result in src (== bufB after 11 stages); x[2n]=Re y[n], x[2n+1]=Im y[n]
  const float s = 1.0f / (float)MH;
  float2* op = (float2*)(out + (size_t)bo * NFFT);
  for (int n = tid; n < MH; n += 256) {
    const float2 y = src[n];
    op[n] = make_float2(y.x * s, y.y * s);
  }
}

extern "C" void kernel_launch(void* const* d_in, const int* in_sizes, int n_in,
                              void* d_out, int out_size, void* d_ws, size_t ws_size,
                              hipStream_t stream) {
  const float* x   = (const float*)d_in[0];
  const float* wr  = (const float*)d_in[1];
  const float* wi  = (const float*)d_in[2];
  const float* br  = (const float*)d_in[3];
  const float* bim = (const float*)d_in[4];
  float* out = (float*)d_out;

  // ws layout: phi0 (4 KB) | zA tiled spectrum, 65*8192*32 float2 = 136.3 MB
  char* ws = (char*)d_ws;
  float*  phi0 = (float*)ws;
  float2* zA   = (float2*)(ws + 4096);

  k_rfft_phase<<<NSIG, 256, 0, stream>>>(x, zA, phi0);
  k_gemm_mode<<<dim3(32, NKT), 256, 0, stream>>>(zA, wr, wi, br, bim, phi0);
  k_irfft<<<NSIG, 256, 0, stream>>>(zA, out);
}

// Round 8
// 630.182 us; speedup vs baseline: 1.9124x; 1.9124x over previous
//
#include <hip/hip_runtime.h>
#include <math.h>

// BATCH=128, IN_CH=OUT_CH=64, DIM=4096, HALF=2049 (=MODES)
#define NFFT 4096
#define MH   2048
#define HALF 2049
#define NSIG 8192
#define KT   32
#define NKT  65
#define PAD(e) ((e) + ((e) >> 3))   // LDS bank-conflict pad (1 per 8 float2)

__device__ __forceinline__ float2 cmulf(float2 a, float2 b) {
  return make_float2(a.x*b.x - a.y*b.y, a.x*b.y + a.y*b.x);
}
__device__ __forceinline__ float2 f2add(float2 a, float2 b){ return make_float2(a.x+b.x, a.y+b.y); }
__device__ __forceinline__ float2 f2sub(float2 a, float2 b){ return make_float2(a.x-b.x, a.y-b.y); }
// multiply by -i (S=-1 fwd) or +i (S=+1 inv)
template<int S> __device__ __forceinline__ float2 mulJ(float2 v){
  return (S < 0) ? make_float2(v.y, -v.x) : make_float2(-v.y, v.x);
}
template<int S> __device__ __forceinline__ void dft4(const float2 a[4], float2 X[4]){
  float2 t0 = f2add(a[0],a[2]), t1 = f2sub(a[0],a[2]);
  float2 t2 = f2add(a[1],a[3]), t3 = f2sub(a[1],a[3]);
  X[0] = f2add(t0,t2); X[2] = f2sub(t0,t2);
  float2 j3 = mulJ<S>(t3);
  X[1] = f2add(t1,j3); X[3] = f2sub(t1,j3);
}
template<int S> __device__ __forceinline__ void dft8(const float2 x[8], float2 X[8]){
  float2 e[4] = {x[0],x[2],x[4],x[6]}, o[4] = {x[1],x[3],x[5],x[7]};
  float2 E[4], O[4]; dft4<S>(e,E); dft4<S>(o,O);
  const float c = 0.70710678118654752f;
  float2 o1 = cmulf(O[1], make_float2(c, (float)S*c));
  float2 o2 = mulJ<S>(O[2]);
  float2 o3 = cmulf(O[3], make_float2(-c, (float)S*c));
  X[0]=f2add(E[0],O[0]); X[4]=f2sub(E[0],O[0]);
  X[1]=f2add(E[1],o1);   X[5]=f2sub(E[1],o1);
  X[2]=f2add(E[2],o2);   X[6]=f2sub(E[2],o2);
  X[3]=f2add(E[3],o3);   X[7]=f2sub(E[3],o3);
}

// 2048-pt complex Stockham FFT (DIF), radix 8*8*8*4, 256 threads, padded LDS buffer.
// Butterfly: x[m] = buf[q + p*s + m*(N/8)]; X = DFT8(x); X[t] *= e^{S*2pi*i*ps*t/N};
// buf[q + 8*p*s + t*s] = X[t].   (twiddle on OUTPUTS — DIF; verified vs DFT by hand)
template<int S>
__device__ __forceinline__ void fft2048(float2* buf, const int tid) {
  #pragma unroll
  for (int lg = 0; lg < 3; ++lg) {          // s = 1, 8, 64
    const int s  = 1 << (3*lg);
    const int q  = tid & (s - 1);
    const int ps = tid - q;                 // p*s
    float2 x[8];
    #pragma unroll
    for (int m = 0; m < 8; ++m) x[m] = buf[PAD(tid + (m << 8))];
    float2 X[8]; dft8<S>(x, X);
    // output twiddles e^{S*2pi*i*ps*t/2048} via recurrence
    const float th = (float)S * (6.283185307179586f / 2048.0f) * (float)ps;
    float sn, cs; __sincosf(th, &sn, &cs);
    const float2 w1 = make_float2(cs, sn);
    float2 wm = w1;
    X[1] = cmulf(X[1], w1);
    #pragma unroll
    for (int m = 2; m < 8; ++m) { wm = cmulf(wm, w1); X[m] = cmulf(X[m], wm); }
    __syncthreads();                        // all reads done before overwrite
    const int base = q + (ps << 3);
    #pragma unroll
    for (int t = 0; t < 8; ++t) buf[PAD(base + s*t)] = X[t];
    __syncthreads();
  }
  { // radix-4 final, s=512, p=0: twiddle-free; reads/writes same slots per thread
    float2 a0[4], a1[4], X0[4], X1[4];
    #pragma unroll
    for (int m = 0; m < 4; ++m) { a0[m] = buf[PAD(tid + (m<<9))]; a1[m] = buf[PAD(tid + 256 + (m<<9))]; }
    dft4<S>(a0, X0); dft4<S>(a1, X1);
    #pragma unroll
    for (int t = 0; t < 4; ++t) { buf[PAD(tid + (t<<9))] = X0[t]; buf[PAD(tid + 256 + (t<<9))] = X1[t]; }
    __syncthreads();
  }
}

// ---------------- K1: rfft(4096) via 2048-pt FFT + unpack + phase align ----------------
__global__ __launch_bounds__(256) void k_rfft_phase(
    const float* __restrict__ x, float2* __restrict__ z, float* __restrict__ phi0) {
  __shared__ float2 buf[2304];
  const int bi  = blockIdx.x;
  const int tid = threadIdx.x;
  const float2* xp = (const float2*)(x + (size_t)bi * NFFT);
  for (int j = tid; j < MH; j += 256) buf[PAD(j)] = xp[j];
  __syncthreads();
  fft2048<-1>(buf, tid);

  // Z[1] (every thread; broadcast reads)
  {
    const float2 Y1 = buf[PAD(1)], Ym = buf[PAD(2047)];
    const float2 E = make_float2(0.5f*(Y1.x + Ym.x), 0.5f*(Y1.y - Ym.y));
    const float2 D = make_float2(0.5f*(Y1.x - Ym.x), 0.5f*(Y1.y + Ym.y));
    float sn, cs; __sincosf(6.283185307179586f / 4096.0f, &sn, &cs);
    const float2 Z1 = make_float2(E.x + (-sn*D.x + cs*D.y), E.y + (-sn*D.y - cs*D.x));
    const float phi = atan2f(Z1.y, Z1.x);
    if (tid == 0 && (bi & 63) == 0) phi0[bi >> 6] = phi;
    for (int k = tid; k < HALF; k += 256) {
      float2 Zk;
      if (k < MH) {
        const float2 Yk = buf[PAD(k)];
        const float2 Ymk = buf[PAD((MH - k) & (MH - 1))];
        const float2 Ek = make_float2(0.5f*(Yk.x + Ymk.x), 0.5f*(Yk.y - Ymk.y));
        const float2 Dk = make_float2(0.5f*(Yk.x - Ymk.x), 0.5f*(Yk.y + Ymk.y));
        float snk, csk; __sincosf(6.283185307179586f * (float)k / 4096.0f, &snk, &csk);
        Zk = make_float2(Ek.x + (-snk*Dk.x + csk*Dk.y), Ek.y + (-snk*Dk.y - csk*Dk.x));
      } else {
        const float2 Y0 = buf[PAD(0)];
        Zk = make_float2(Y0.x - Y0.y, 0.0f);
      }
      const int kin = (k <= 1024) ? k : k - HALF;
      double rev = (double)phi * (double)kin * 0.15915494309189535;
      rev -= rint(rev);
      const float thr = (float)(rev * 6.283185307179586);
      float snr, csr; __sincosf(thr, &snr, &csr);
      const float2 r = make_float2(Zk.x*csr + Zk.y*snr, Zk.y*csr - Zk.x*snr);
      z[((size_t)(k >> 5) * NSIG + bi) * KT + (k & 31)] = r;
    }
  }
}

// ---------------- K2: per-mode complex GEMM + bias + e^{+i phi0 k_out}, IN-PLACE --------
// zio[kt][bi][kk] -> zio[kt][bo][kk].  Block: (kt, 4 b) x 64 o x 32 kk; z LDS double-buf.
__global__ __launch_bounds__(256) void k_gemm_mode(
    float2* __restrict__ zio,
    const float* __restrict__ wr, const float* __restrict__ wi,
    const float* __restrict__ br, const float* __restrict__ bim,
    const float* __restrict__ phi0) {
  __shared__ float4 zst[2][4][128];       // [dbuf][b][8i x 32kk as float4] = 16 KB
  const int t  = threadIdx.x;
  const int kk = t & 31;
  const int g  = t >> 5;                  // 0..7
  const int o0 = g * 8;
  const int kt = blockIdx.y;
  const int b0 = blockIdx.x * 4;
  const int k  = kt * KT + kk;
  const bool kvalid = (k < HALF);
  const int kc = kvalid ? k : (HALF - 1);

  const int sb = t >> 6;                  // staging: b row (0..3)
  const int sh = t & 63;                  // staging: lane within row chunk

  float2 acc[4][8];
  #pragma unroll
  for (int bb = 0; bb < 4; ++bb)
    #pragma unroll
    for (int oo = 0; oo < 8; ++oo) acc[bb][oo] = make_float2(0.f, 0.f);

  const size_t tilebase = (size_t)kt * NSIG * KT;

  { // prologue: stage chunk 0 (i = 0..7)
    const float4* s4 = (const float4*)(zio + tilebase + (size_t)((b0 + sb) * 64) * KT);
    zst[0][sb][sh]      = s4[sh];
    zst[0][sb][sh + 64] = s4[sh + 64];
  }

  #pragma unroll 1
  for (int c = 0; c < 8; ++c) {
    float4 p0, p1;
    if (c < 7) {
      const float4* s4 = (const float4*)(zio + tilebase + (size_t)((b0 + sb) * 64 + (c + 1) * 8) * KT);
      p0 = s4[sh]; p1 = s4[sh + 64];
    }
    __syncthreads();
    #pragma unroll 2
    for (int il = 0; il < 8; ++il) {
      const int i = c * 8 + il;
      float2 zv[4];
      #pragma unroll
      for (int bb = 0; bb < 4; ++bb)
        zv[bb] = ((const float2*)&zst[c & 1][bb][0])[il * KT + kk];
      const float* wrp = wr + ((size_t)i * 64 + o0) * HALF + kc;
      const float* wip = wi + ((size_t)i * 64 + o0) * HALF + kc;
      float wvr[8], wvi[8];
      #pragma unroll
      for (int oo = 0; oo < 8; ++oo) { wvr[oo] = wrp[(size_t)oo * HALF]; wvi[oo] = wip[(size_t)oo * HALF]; }
      #pragma unroll
      for (int oo = 0; oo < 8; ++oo)
        #pragma unroll
        for (int bb = 0; bb < 4; ++bb) {
          acc[bb][oo].x += zv[bb].x * wvr[oo] - zv[bb].y * wvi[oo];
          acc[bb][oo].y += zv[bb].x * wvi[oo] + zv[bb].y * wvr[oo];
        }
    }
    if (c < 7) {
      zst[(c + 1) & 1][sb][sh]      = p0;
      zst[(c + 1) & 1][sb][sh + 64] = p1;
    }
  }
  __syncthreads();   // all staging global reads complete -> safe to overwrite in place

  const int kout = (k <= 1024) ? k : k - HALF;
  #pragma unroll
  for (int bb = 0; bb < 4; ++bb) {
    double rev = (double)phi0[b0 + bb] * (double)kout * 0.15915494309189535;
    rev -= rint(rev);
    const float th = (float)(rev * 6.283185307179586);
    float sn, cs; __sincosf(th, &sn, &cs);
    const float2 rot = make_float2(cs, sn);
    #pragma unroll
    for (int oo = 0; oo < 8; ++oo) {
      const int o = o0 + oo;
      const float2 v = make_float2(acc[bb][oo].x + br[(size_t)o * HALF + kc],
                                   acc[bb][oo].y + bim[(size_t)o * HALF + kc]);
      if (kvalid)
        zio[tilebase + (size_t)((b0 + bb) * 64 + o) * KT + kk] = cmulf(v, rot);
    }
  }
}

// ---------------- K3: irfft(4096): pack pairs from global + inverse FFT ----------------
__global__ __launch_bounds__(256) void k_irfft(
    const float2* __restrict__ oft, float* __restrict__ out) {
  __shared__ float2 buf[2304];
  const int bo  = blockIdx.x;
  const int tid = threadIdx.x;

  // Y[k] = 0.5*(A + i e^{+2pi i k/4096} D);  A = Zk + conj(Zm), D = Zk - conj(Zm), m = 2048-k
  for (int k = tid; k <= 1024; k += 256) {
    const float2 Zk_raw = oft[((size_t)(k >> 5) * NSIG + bo) * KT + (k & 31)];
    if (k == 0) {
      const float2 Zn_raw = oft[((size_t)(MH >> 5) * NSIG + bo) * KT + 0];
      const float2 Zk = make_float2(Zk_raw.x, 0.f);
      const float2 Zm = make_float2(Zn_raw.x, 0.f);
      buf[PAD(0)] = make_float2(0.5f * (Zk.x + Zm.x), 0.5f * (Zk.x - Zm.x));
    } else {
      const int m = MH - k;
      const float2 Zm_raw = (k == 1024) ? Zk_raw
          : oft[((size_t)(m >> 5) * NSIG + bo) * KT + (m & 31)];
      { // Y[k]
        const float2 A = make_float2(Zk_raw.x + Zm_raw.x, Zk_raw.y - Zm_raw.y);
        const float2 D = make_float2(Zk_raw.x - Zm_raw.x, Zk_raw.y + Zm_raw.y);
        float sn, cs; __sincosf(6.283185307179586f * (float)k / 4096.0f, &sn, &cs);
        buf[PAD(k)] = make_float2(0.5f*(A.x + (-sn*D.x - cs*D.y)),
                                  0.5f*(A.y + (-sn*D.y + cs*D.x)));
      }
      if (k != 1024) { // Y[m]
        const float2 A = make_float2(Zm_raw.x + Zk_raw.x, Zm_raw.y - Zk_raw.y);
        const float2 D = make_float2(Zm_raw.x - Zk_raw.x, Zm_raw.y + Zk_raw.y);
        float sn, cs; __sincosf(6.283185307179586f * (float)m / 4096.0f, &sn, &cs);
        buf[PAD(m)] = make_float2(0.5f*(A.x + (-sn*D.x - cs*D.y)),
                                  0.5f*(A.y + (-sn*D.y + cs*D.x)));
      }
    }
  }
  __syncthreads();
  fft2048<1>(buf, tid);

  const float s = 1.0f / (float)MH;
  float2* op = (float2*)(out + (size_t)bo * NFFT);
  for (int n = tid; n < MH; n += 256) {
    const float2 y = buf[PAD(n)];
    op[n] = make_float2(y.x * s, y.y * s);
  }
}

extern "C" void kernel_launch(void* const* d_in, const int* in_sizes, int n_in,
                              void* d_out, int out_size, void* d_ws, size_t ws_size,
                              hipStream_t stream) {
  const float* x   = (const float*)d_in[0];
  const float* wr  = (const float*)d_in[1];
  const float* wi  = (const float*)d_in[2];
  const float* br  = (const float*)d_in[3];
  const float* bim = (const float*)d_in[4];
  float* out = (float*)d_out;

  // ws: phi0 (4 KB) | zA tiled spectrum, 65*8192*32 float2 = 136.3 MB (in-place GEMM)
  char* ws = (char*)d_ws;
  float*  phi0 = (float*)ws;
  float2* zA   = (float2*)(ws + 4096);

  k_rfft_phase<<<NSIG, 256, 0, stream>>>(x, zA, phi0);
  k_gemm_mode<<<dim3(32, NKT), 256, 0, stream>>>(zA, wr, wi, br, bim, phi0);
  k_irfft<<<NSIG, 256, 0, stream>>>(zA, out);
}